// Round 2
// baseline (323.300 us; speedup 1.0000x reference)
//
#include <hip/hip_runtime.h>
#include <hip/hip_bf16.h>

// AttnBlock: x[4,512,64,64] fp32. GroupNorm(8) -> qkv 1x1conv -> attn -> proj -> +xn
// Q,K,V,P all fp8 e4m3. S = exp(Q.K^T*scale), H = P.V via MX-fp8 MFMA (unit scales).
// R7: smx/hgemm rebuilt as mx_gemm: 256x256 tile, 8 waves, MFMA 32x32x64_f8f6f4,
// K-step 64, 4 rotating LDS slots (128KB), depth-3 prefetch with COUNTED vmcnt
// (steady-state vmcnt(8), never 0 until the tail) + single barrier/iter (T3+T4).
// LDS: 2 rows per 128B line, 16B-chunk XOR swizzle; stage side pre-inverts the
// swizzle in the global source address (linear global_load_lds dests).

typedef unsigned short u16;
typedef unsigned char u8;
typedef __bf16 bf16x8 __attribute__((ext_vector_type(8)));
typedef float f32x4 __attribute__((ext_vector_type(4)));
typedef float f32x16 __attribute__((ext_vector_type(16)));
typedef int i32x4 __attribute__((ext_vector_type(4)));
typedef int i32x8 __attribute__((ext_vector_type(8)));
typedef unsigned short u16x4 __attribute__((ext_vector_type(4)));
typedef unsigned short u16x8 __attribute__((ext_vector_type(8)));

#define CDIM 512
#define NPOS 4096
#define NBATCH 4

__device__ __forceinline__ u16 f2bf(float x) {
  union { float f; unsigned u; } c; c.f = x;
  unsigned u = c.u;
  u += 0x7fffu + ((u >> 16) & 1u);   // round-to-nearest-even
  return (u16)(u >> 16);
}
__device__ __forceinline__ float bf2f(u16 h) {
  union { unsigned u; float f; } c; c.u = ((unsigned)h) << 16;
  return c.f;
}
// pack 4 floats -> 4 fp8 e4m3 bytes
__device__ __forceinline__ unsigned pk4_fp8(float a, float b, float c, float d) {
  unsigned v = __builtin_amdgcn_cvt_pk_fp8_f32(a, b, 0, false);
  v = __builtin_amdgcn_cvt_pk_fp8_f32(c, d, v, true);
  return v;
}

__device__ __forceinline__ void async16(const u16* g, u16* l) {
  __builtin_amdgcn_global_load_lds(
      (const __attribute__((address_space(1))) unsigned int*)g,
      (__attribute__((address_space(3))) unsigned int*)l, 16, 0, 0);
}
__device__ __forceinline__ void async16b(const u8* g, u8* l) {
  __builtin_amdgcn_global_load_lds(
      (const __attribute__((address_space(1))) unsigned int*)g,
      (__attribute__((address_space(3))) unsigned int*)l, 16, 0, 0);
}

__device__ __forceinline__ void drain_barrier() {
  asm volatile("s_waitcnt vmcnt(0)" ::: "memory");
  __builtin_amdgcn_s_barrier();
}

__device__ __forceinline__ float wred_sum(float v) {
#pragma unroll
  for (int o = 32; o > 0; o >>= 1) v += __shfl_xor(v, o, 64);
  return v;
}

// ---------------- GroupNorm stats: 32 (b,g) groups x 8 slices ----------------
__global__ __launch_bounds__(256) void gn_partial(const float* __restrict__ x,
                                                  float* __restrict__ stats) {
  int gidx = blockIdx.x >> 3;
  int slice = blockIdx.x & 7;
  const float4* src = (const float4*)x + (long)gidx * 65536 + (long)slice * 8192;
  float s = 0.f, ss = 0.f;
  for (int i = threadIdx.x; i < 8192; i += 256) {
    float4 v = src[i];
    s  += v.x + v.y + v.z + v.w;
    ss += v.x * v.x + v.y * v.y + v.z * v.z + v.w * v.w;
  }
  s = wred_sum(s); ss = wred_sum(ss);
  __shared__ float r1[4], r2[4];
  int lane = threadIdx.x & 63, wave = threadIdx.x >> 6;
  if (lane == 0) { r1[wave] = s; r2[wave] = ss; }
  __syncthreads();
  if (threadIdx.x == 0) {
    atomicAdd(&stats[gidx * 2 + 0], r1[0] + r1[1] + r1[2] + r1[3]);
    atomicAdd(&stats[gidx * 2 + 1], r2[0] + r2[1] + r2[2] + r2[3]);
  }
}

// ------- normalize + write xnb bf16 [b,c,p] (residual) and xnT bf16 [b,p,c] -------
__global__ __launch_bounds__(256) void norm_trans(const float* __restrict__ x,
                                                  const float* __restrict__ stats,
                                                  const float* __restrict__ gamma,
                                                  const float* __restrict__ beta,
                                                  u16* __restrict__ xnb,
                                                  u16* __restrict__ xnT) {
  __shared__ float tile[32][33];
  int b = blockIdx.z, c0 = blockIdx.y * 32, p0 = blockIdx.x * 32;
  int g = (b << 3) + (c0 >> 6);
  float cnt = 1.f / 262144.f;
  float mu = stats[g * 2 + 0] * cnt;
  float ms = stats[g * 2 + 1] * cnt;
  float rstd = rsqrtf(ms - mu * mu + 1e-5f);
  int tp = threadIdx.x & 31, tc = threadIdx.x >> 5;
#pragma unroll
  for (int r = 0; r < 4; r++) {
    int cl = tc + r * 8;
    int c = c0 + cl;
    long idx = ((long)(b * CDIM + c)) * NPOS + p0 + tp;
    float v = (x[idx] - mu) * rstd * gamma[c] + beta[c];
    xnb[idx] = f2bf(v);
    tile[cl][tp] = v;
  }
  __syncthreads();
#pragma unroll
  for (int r = 0; r < 4; r++) {
    int pl = tc + r * 8, cl = tp;
    xnT[((long)(b * NPOS + p0 + pl)) * CDIM + c0 + cl] = f2bf(tile[cl][pl]);
  }
}

// ------- fp32 -> bf16 weight convert; wp gets duplicated to [512][1024] = [wp|wp] -------
__global__ __launch_bounds__(256) void cvt4(const float* __restrict__ a, const float* __restrict__ b,
                                            const float* __restrict__ c, const float* __restrict__ d,
                                            u16* __restrict__ oa, u16* __restrict__ ob,
                                            u16* __restrict__ oc, u16* __restrict__ od) {
  int i = blockIdx.x * 256 + threadIdx.x;
  if (blockIdx.y == 3) {
    int m = i >> 9, k = i & 511;
    u16 v = f2bf(d[i]);
    od[m * 1024 + k] = v;
    od[m * 1024 + 512 + k] = v;
    return;
  }
  const float* src; u16* dst;
  switch (blockIdx.y) {
    case 0: src = a; dst = oa; break;
    case 1: src = b; dst = ob; break;
    default: src = c; dst = oc; break;
  }
  dst[i] = f2bf(src[i]);
}

// ---------------- gemm_bt: C[m,n] = sum_k A[m,k]*B[n,k]  (both K-contig, bf16) ----------------
// 128(M) x BN tile, BK=64, BN/64*2 waves (wave tile 64x64), XOR-swizzled LDS.
// Double-buffered: stage tile t+1 before computing tile t; one barrier + vmcnt(0)/iter.
// MFMA operands SWAPPED: mfma(bfr, af, acc) -> C/D lane dim = m, reg dim = n.
// MODE 0: fp8 out, + bias[n] (bias|bias1 split at n=512)    (fused QK -> fp8)
// MODE 4: f32  out = acc/laux[n] + bias[m] + bf16 resid     (proj + 1/l + residual)
// MODE 5: fp8 out, + bias[m]                                (V fp8)
template <int MODE, int BN>
__global__ __launch_bounds__(BN * 2, 2) void gemm_bt(
    const u16* __restrict__ A, const u16* __restrict__ B,
    void* __restrict__ Cp, const float* __restrict__ bias,
    const float* __restrict__ bias1, const u16* __restrict__ residb,
    const float* __restrict__ laux,
    int N, int K, int lda, int ldb,
    long sA, long sB, long sC, long sR) {
  __shared__ u16 Asm[2][128 * 64];
  __shared__ u16 Bsm[2][BN * 64];
  constexpr int NT = BN * 2;       // threads
  constexpr int STEP = NT / 8;     // staging rows per round
  int bz = blockIdx.z;
  A += (long)bz * sA;
  B += (long)bz * sB;
  int bm = blockIdx.y, bn = blockIdx.x;
  int tid = threadIdx.x;
  int lane = tid & 63, wave = tid >> 6;
  int wm = (wave & 1) * 64, wn = (wave >> 1) * 64;

  int row0 = tid >> 3;             // 0..STEP-1
  int ko = (tid & 7) * 8;
  int kos = ko ^ ((row0 & 7) * 8); // STEP multiple of 8 -> row&7 invariant
  f32x4 acc[4][4] = {};
  int row16 = lane & 15;
  int kq = (lane >> 4) * 8;

  auto stage = [&](int buf, int k0) {
#pragma unroll
    for (int r = 0; r < 128 / STEP; r++) {
      int row = row0 + r * STEP;
      async16(A + (long)(bm * 128 + row) * lda + k0 + kos, &Asm[buf][row * 64 + ko]);
    }
#pragma unroll
    for (int r = 0; r < BN / STEP; r++) {
      int row = row0 + r * STEP;
      async16(B + (long)(bn * BN + row) * ldb + k0 + kos, &Bsm[buf][row * 64 + ko]);
    }
  };

  stage(0, 0);
  drain_barrier();
  int cur = 0;
  for (int k0 = 0; k0 < K; k0 += 64) {
    if (k0 + 64 < K) stage(cur ^ 1, k0 + 64);   // prefetch next tile (in flight during MFMA)
#pragma unroll
    for (int s2 = 0; s2 < 2; s2++) {
      bf16x8 af[4], bfr[4];
#pragma unroll
      for (int i = 0; i < 4; i++) {
        int row = wm + i * 16 + row16;
        af[i] = *(const bf16x8*)&Asm[cur][row * 64 + ((s2 * 32 + kq) ^ ((row & 7) * 8))];
      }
#pragma unroll
      for (int j = 0; j < 4; j++) {
        int row = wn + j * 16 + row16;
        bfr[j] = *(const bf16x8*)&Bsm[cur][row * 64 + ((s2 * 32 + kq) ^ ((row & 7) * 8))];
      }
      __builtin_amdgcn_s_setprio(1);
#pragma unroll
      for (int i = 0; i < 4; i++)
#pragma unroll
        for (int j = 0; j < 4; j++)
          acc[i][j] = __builtin_amdgcn_mfma_f32_16x16x32_bf16(bfr[j], af[i], acc[i][j], 0, 0, 0);
      __builtin_amdgcn_s_setprio(0);
    }
    drain_barrier();
    cur ^= 1;
  }

  // epilogue (swapped layout): m = lane&15 within tile, n = (lane>>4)*4 + reg
  int mcol = lane & 15, rb = (lane >> 4) * 4;
  long zC = (long)bz * sC;
#pragma unroll
  for (int i = 0; i < 4; i++) {
    int gm = bm * 128 + wm + i * 16 + mcol;
    float bm_add = 0.f;
    if constexpr (MODE == 4 || MODE == 5) bm_add = bias[gm];
#pragma unroll
    for (int j = 0; j < 4; j++) {
      int gn0 = bn * BN + wn + j * 16 + rb;
      long off = zC + (long)gm * N + gn0;
      float v[4];
#pragma unroll
      for (int r = 0; r < 4; r++) v[r] = acc[i][j][r];
      if constexpr (MODE == 0) {
        const float* bb = (gn0 < 512) ? (bias + gn0) : (bias1 + (gn0 - 512));
#pragma unroll
        for (int r = 0; r < 4; r++) v[r] += bb[r];
        *(unsigned*)&((u8*)Cp)[off] = pk4_fp8(v[0], v[1], v[2], v[3]);
      }
      if constexpr (MODE == 4) {
        f32x4 lv = *(const f32x4*)&laux[bz * NPOS + gn0];
        u16x4 rv = *(const u16x4*)&residb[(long)bz * sR + (long)gm * N + gn0];
        f32x4 o;
#pragma unroll
        for (int r = 0; r < 4; r++) o[r] = v[r] / lv[r] + bm_add + bf2f(rv[r]);
        *(f32x4*)&((float*)Cp)[off] = o;
      }
      if constexpr (MODE == 5) {
#pragma unroll
        for (int r = 0; r < 4; r++) v[r] += bm_add;
        *(unsigned*)&((u8*)Cp)[off] = pk4_fp8(v[0], v[1], v[2], v[3]);
      }
    }
  }
}

// ---------------- mx_gemm: deep-pipelined MX-fp8 GEMM (32x32x64 f8f6f4) ----------------
// Block: 512 thr / 8 waves (2M x 4N), tile 256(M) x 256(N), wave tile 128x64.
// K-step 64. LDS: 4 rotating slots x (A 16KB + B 16KB) = 128KB. Depth-3 prefetch,
// counted vmcnt (steady state vmcnt(8); 0 only at the tail), ONE barrier per iter.
// LDS layout per slot: 2 global rows per 128B line; 16B chunk XOR-swizzled by
// (ldsrow&7); stage pre-inverts the swizzle in the GLOBAL src addr (linear dests).
// MFMA swapped: mfma(bf, af, acc) -> D lane dim = m(i), reg dim = n.
// MODE 0: smx  — A=Q rows, B=K rows (QKf8, stride 1024), out = exp(acc*scale) fp8
//                P[b,i,j] + rowsum atomics into l. TSTEPS=8.
// MODE 1: hgemm — A=P rows, B=V rows (stride 4096), split-K=2 via z=(b<<1)|sp,
//                out bf16 part[b][i][sp*512+c] (row stride 1024). TSTEPS=32.
template <int MODE, int TSTEPS, int LDAB>
__global__ __launch_bounds__(512, 1) void mx_gemm(
    const u8* __restrict__ Abase, const u8* __restrict__ Bbase,
    void* __restrict__ Out, float* __restrict__ l, float scale) {
  __shared__ u8 S[4][2][16384];
  int tid = threadIdx.x, lane = tid & 63, w = tid >> 6;
  int wm = (w & 1) * 128, wn = (w >> 1) * 64;
  int bm = blockIdx.y, bn = blockIdx.x, bz = blockIdx.z;
  int l31 = lane & 31, h = lane >> 5;

  const u8 *Ab, *Bb;
  if constexpr (MODE == 0) {
    Ab = Abase + (long)bz * 4194304;
    Bb = Ab + 512;
  } else {
    int b = bz >> 1, sp = bz & 1;
    Ab = Abase + (long)b * 16777216 + sp * 2048;
    Bb = Bbase + (long)b * 2097152 + sp * 2048;
  }

  f32x16 acc[4][2] = {};

  // stage one K-step (64 cols) of A(256 rows) + B(256 rows) into slot.
  // LDS chunk z (16B): ldsrow=z>>3, pos=z&7, gch=pos^(ldsrow&7),
  // row=ldsrow*2+(gch>>2), col16=gch&3.
  auto stage = [&](int slot, int k0) {
    u8* dA = &S[slot][0][0];
    u8* dB = &S[slot][1][0];
#pragma unroll
    for (int half = 0; half < 2; half++) {
      int z = tid + half * 512;
      int ldsrow = z >> 3;
      int gch = (z & 7) ^ (ldsrow & 7);
      int row = ldsrow * 2 + (gch >> 2);
      int c16 = gch & 3;
      async16b(Ab + (long)(bm * 256 + row) * LDAB + k0 + c16 * 16, dA + z * 16);
      async16b(Bb + (long)(bn * 256 + row) * LDAB + k0 + c16 * 16, dB + z * 16);
    }
  };

  stage(0, 0);
  stage(1, 64);
  stage(2, 128);

  for (int t = 0; t < TSTEPS; t++) {
    // drain stage t only; keep up to 2 newer stages (8 loads) in flight
    if (t < TSTEPS - 2)      { asm volatile("s_waitcnt vmcnt(8)" ::: "memory"); }
    else if (t == TSTEPS - 2){ asm volatile("s_waitcnt vmcnt(4)" ::: "memory"); }
    else                     { asm volatile("s_waitcnt vmcnt(0)" ::: "memory"); }
    __builtin_amdgcn_s_barrier();
    __builtin_amdgcn_sched_barrier(0);
    if (t + 3 < TSTEPS) stage((t + 3) & 3, (t + 3) * 64);   // overwrites slot (t-1)&3: WAR safe

    int slot = t & 3;
    const u8* As = &S[slot][0][0];
    const u8* Bs = &S[slot][1][0];
    i32x8 af[4], bf[2];
#pragma unroll
    for (int mr = 0; mr < 4; mr++) {
      int r = wm + mr * 32 + l31;
      int lr = r >> 1, sw = lr & 7;
      int g0 = (r & 1) * 4 + h * 2;
      i32x4 lo = *(const i32x4*)&As[lr * 128 + ((g0 ^ sw) * 16)];
      i32x4 hi = *(const i32x4*)&As[lr * 128 + (((g0 + 1) ^ sw) * 16)];
      af[mr] = __builtin_shufflevector(lo, hi, 0, 1, 2, 3, 4, 5, 6, 7);
    }
#pragma unroll
    for (int nr = 0; nr < 2; nr++) {
      int r = wn + nr * 32 + l31;
      int lr = r >> 1, sw = lr & 7;
      int g0 = (r & 1) * 4 + h * 2;
      i32x4 lo = *(const i32x4*)&Bs[lr * 128 + ((g0 ^ sw) * 16)];
      i32x4 hi = *(const i32x4*)&Bs[lr * 128 + (((g0 + 1) ^ sw) * 16)];
      bf[nr] = __builtin_shufflevector(lo, hi, 0, 1, 2, 3, 4, 5, 6, 7);
    }
    __builtin_amdgcn_s_setprio(1);
#pragma unroll
    for (int mr = 0; mr < 4; mr++)
#pragma unroll
      for (int nr = 0; nr < 2; nr++)
        acc[mr][nr] = __builtin_amdgcn_mfma_scale_f32_32x32x64_f8f6f4(
            bf[nr], af[mr], acc[mr][nr], 0, 0, 0, 0x7F7F7F7F, 0, 0x7F7F7F7F);
    __builtin_amdgcn_s_setprio(0);
  }

  // epilogue (swapped 32x32): i = lane&31; n = (reg&3) + 8*(reg>>2) + 4*h
  if constexpr (MODE == 0) {
    long zC = (long)bz * 16777216;
    u8* P = (u8*)Out;
    float rsum[4] = {0.f, 0.f, 0.f, 0.f};
#pragma unroll
    for (int mr = 0; mr < 4; mr++) {
      int gi = bm * 256 + wm + mr * 32 + l31;
#pragma unroll
      for (int nr = 0; nr < 2; nr++) {
        int jb = bn * 256 + wn + nr * 32 + h * 4;
#pragma unroll
        for (int g = 0; g < 4; g++) {
          float v0 = __expf(acc[mr][nr][g * 4 + 0] * scale);
          float v1 = __expf(acc[mr][nr][g * 4 + 1] * scale);
          float v2 = __expf(acc[mr][nr][g * 4 + 2] * scale);
          float v3 = __expf(acc[mr][nr][g * 4 + 3] * scale);
          rsum[mr] += v0 + v1 + v2 + v3;
          *(unsigned*)&P[zC + (long)gi * 4096 + jb + 8 * g] = pk4_fp8(v0, v1, v2, v3);
        }
      }
    }
#pragma unroll
    for (int mr = 0; mr < 4; mr++) rsum[mr] += __shfl_xor(rsum[mr], 32, 64);
    if (lane < 32) {
      int base = bz * NPOS + bm * 256 + wm + l31;
#pragma unroll
      for (int mr = 0; mr < 4; mr++) atomicAdd(&l[base + mr * 32], rsum[mr]);
    }
  } else {
    int b = bz >> 1, sp = bz & 1;
    long zC = (long)b * 4194304 + sp * 512;
    u16* part = (u16*)Out;
#pragma unroll
    for (int mr = 0; mr < 4; mr++) {
      int gi = bm * 256 + wm + mr * 32 + l31;
#pragma unroll
      for (int nr = 0; nr < 2; nr++) {
        int cb = bn * 256 + wn + nr * 32 + h * 4;
#pragma unroll
        for (int g = 0; g < 4; g++) {
          u16x4 o;
          o[0] = f2bf(acc[mr][nr][g * 4 + 0]);
          o[1] = f2bf(acc[mr][nr][g * 4 + 1]);
          o[2] = f2bf(acc[mr][nr][g * 4 + 2]);
          o[3] = f2bf(acc[mr][nr][g * 4 + 3]);
          *(u16x4*)&part[zC + (long)gi * 1024 + cb + 8 * g] = o;
        }
      }
    }
  }
}

extern "C" void kernel_launch(void* const* d_in, const int* in_sizes, int n_in,
                              void* d_out, int out_size, void* d_ws, size_t ws_size,
                              hipStream_t stream) {
  const float* x     = (const float*)d_in[0];
  const float* gamma = (const float*)d_in[1];
  const float* beta  = (const float*)d_in[2];
  const float* wq = (const float*)d_in[3];
  const float* bq = (const float*)d_in[4];
  const float* wk = (const float*)d_in[5];
  const float* bk = (const float*)d_in[6];
  const float* wv = (const float*)d_in[7];
  const float* bv = (const float*)d_in[8];
  const float* wp = (const float*)d_in[9];
  const float* bp = (const float*)d_in[10];
  float* out = (float*)d_out;

  // workspace layout (bytes), total ~163 MB
  char* W = (char*)d_ws;
  float* stats = (float*)(W + 0);               // 256 B
  float* l     = (float*)(W + 256);             // 65,536 B (row sums)
  u16* xnb  = (u16*)(W + 65792);                // 16,777,216 bf16 [b,c,p] residual
  u16* xnT  = (u16*)(W + 16843008);             // 16,777,216 bf16 [b,p,c]
  u16* wqkb = (u16*)(W + 33620224);             // 1,048,576  bf16 [1024(cq;ck)][512]
  u16* wvb  = (u16*)(W + 34668800);             // 524,288    bf16 [512][512]
  u16* wpd  = (u16*)(W + 35193088);             // 2,097,152  bf16 [512][1024] = [wp|wp]
  u8*  QKf8 = (u8*)(W + 37290240);              // 16,777,216 fp8 [b,p,1024] (Q|K)
  u8*  Vf8  = (u8*)(W + 54067456);              // 8,388,608  fp8 [b,c,p]
  u16* part = (u16*)(W + 62456064);             // 33,554,432 bf16 [b,i,1024] (H partials)
  u8*  SP   = (u8*)(W + 96010496);              // 67,108,864 fp8 [b,i,j]
  (void)in_sizes; (void)n_in; (void)out_size; (void)ws_size;

  hipMemsetAsync(W, 0, 65792, stream);   // stats + l
  gn_partial<<<256, 256, 0, stream>>>(x, stats);
  norm_trans<<<dim3(128, 16, 4), 256, 0, stream>>>(x, stats, gamma, beta, xnb, xnT);
  cvt4<<<dim3(1024, 4), 256, 0, stream>>>(wq, wk, wv, wp, wqkb, wqkb + 262144, wvb, wpd);

  const long NC = (long)NPOS * CDIM;    // 2,097,152
  const long CN = (long)CDIM * NPOS;
  const float scale = 0.044194173824159216f;  // 1/sqrt(512)

  // QKf8[b*p, 0:512]=Q, [512:1024]=K (fp8): A=xnT (M=16384), B=wqkb (N=1024), K=512
  gemm_bt<0, 128><<<dim3(8, 128, 1), 256, 0, stream>>>(xnT, wqkb, QKf8, bq, bk, nullptr, nullptr,
      1024, CDIM, CDIM, CDIM, 0, 0, 0, 0);
  // V fp8 [b][c, p] = wv . xnT_b^T + bv  (M=512, N=4096, K=512)
  gemm_bt<5, 128><<<dim3(32, 4, 4), 256, 0, stream>>>(wvb, xnT, Vf8, bv, nullptr, nullptr, nullptr,
      NPOS, CDIM, CDIM, CDIM, 0, NC, CN, 0);
  // P fp8 = exp(Q.K^T * scale), rowsums -> l  (MX-fp8 32x32x64, M=N=4096, K=512)
  mx_gemm<0, 8, 1024><<<dim3(16, 16, NBATCH), 512, 0, stream>>>(QKf8, nullptr, SP, l, scale);
  // H partials (bf16): part[b][i][sp*512+c] = P_b[:, sp*2048:+2048] . V_b[:, ...]^T
  mx_gemm<1, 32, 4096><<<dim3(2, 16, 8), 512, 0, stream>>>(SP, Vf8, part, nullptr, 0.f);
  // out[b][c, p] = (wpd . part_b^T)/l + bp + xnb  (M=512, N=4096, K=1024)
  gemm_bt<4, 128><<<dim3(32, 4, 4), 256, 0, stream>>>(wpd, part, (void*)out, bp, nullptr, xnb, l,
      NPOS, 1024, 1024, 1024, 0, (long)NPOS * 1024, CN, CN);
}

// Round 3
// 282.630 us; speedup vs baseline: 1.1439x; 1.1439x over previous
//
#include <hip/hip_runtime.h>
#include <hip/hip_bf16.h>

// AttnBlock: x[4,512,64,64] fp32. GroupNorm(8) -> qkv 1x1conv -> attn -> proj -> +xn
// Q,K,V,P fp8 e4m3. R8: FLASH FUSION — S=exp(QK^T*scale) and H=P.V fused in one
// kernel (fattn), eliminating the 67MB P round-trip + l atomics + one launch.
// fattn: 256 blocks (64 i-tiles x 4 batch), 512 thr / 8 waves, j-tile 128,
// 32 steps of {stage V_t || QK (K=512, MX 32x32x64) -> exp -> P(8KB LDS fp8)}
// then {stage K_t+1 || acc += P.V^T (K=128)}. K/V single-buffered (64KB each),
// stage issued one phase ahead (min-2-phase template). Rowsums reduced in-regs,
// H = (P.V)/l stored bf16 [b,i,512]; proj GEMM now K=512 (no [wp|wp] dup).

typedef unsigned short u16;
typedef unsigned char u8;
typedef __bf16 bf16x8 __attribute__((ext_vector_type(8)));
typedef float f32x4 __attribute__((ext_vector_type(4)));
typedef float f32x16 __attribute__((ext_vector_type(16)));
typedef int i32x4 __attribute__((ext_vector_type(4)));
typedef int i32x8 __attribute__((ext_vector_type(8)));
typedef unsigned short u16x4 __attribute__((ext_vector_type(4)));

#define CDIM 512
#define NPOS 4096
#define NBATCH 4

__device__ __forceinline__ u16 f2bf(float x) {
  union { float f; unsigned u; } c; c.f = x;
  unsigned u = c.u;
  u += 0x7fffu + ((u >> 16) & 1u);   // round-to-nearest-even
  return (u16)(u >> 16);
}
__device__ __forceinline__ float bf2f(u16 h) {
  union { unsigned u; float f; } c; c.u = ((unsigned)h) << 16;
  return c.f;
}
// pack 4 floats -> 4 fp8 e4m3 bytes
__device__ __forceinline__ unsigned pk4_fp8(float a, float b, float c, float d) {
  unsigned v = __builtin_amdgcn_cvt_pk_fp8_f32(a, b, 0, false);
  v = __builtin_amdgcn_cvt_pk_fp8_f32(c, d, v, true);
  return v;
}

__device__ __forceinline__ void async16(const u16* g, u16* l) {
  __builtin_amdgcn_global_load_lds(
      (const __attribute__((address_space(1))) unsigned int*)g,
      (__attribute__((address_space(3))) unsigned int*)l, 16, 0, 0);
}
__device__ __forceinline__ void async16b(const u8* g, u8* l) {
  __builtin_amdgcn_global_load_lds(
      (const __attribute__((address_space(1))) unsigned int*)g,
      (__attribute__((address_space(3))) unsigned int*)l, 16, 0, 0);
}

__device__ __forceinline__ void drain_barrier() {
  asm volatile("s_waitcnt vmcnt(0)" ::: "memory");
  __builtin_amdgcn_s_barrier();
}

__device__ __forceinline__ float wred_sum(float v) {
#pragma unroll
  for (int o = 32; o > 0; o >>= 1) v += __shfl_xor(v, o, 64);
  return v;
}

// ---------------- GroupNorm stats: 32 (b,g) groups x 8 slices ----------------
__global__ __launch_bounds__(256) void gn_partial(const float* __restrict__ x,
                                                  float* __restrict__ stats) {
  int gidx = blockIdx.x >> 3;
  int slice = blockIdx.x & 7;
  const float4* src = (const float4*)x + (long)gidx * 65536 + (long)slice * 8192;
  float s = 0.f, ss = 0.f;
  for (int i = threadIdx.x; i < 8192; i += 256) {
    float4 v = src[i];
    s  += v.x + v.y + v.z + v.w;
    ss += v.x * v.x + v.y * v.y + v.z * v.z + v.w * v.w;
  }
  s = wred_sum(s); ss = wred_sum(ss);
  __shared__ float r1[4], r2[4];
  int lane = threadIdx.x & 63, wave = threadIdx.x >> 6;
  if (lane == 0) { r1[wave] = s; r2[wave] = ss; }
  __syncthreads();
  if (threadIdx.x == 0) {
    atomicAdd(&stats[gidx * 2 + 0], r1[0] + r1[1] + r1[2] + r1[3]);
    atomicAdd(&stats[gidx * 2 + 1], r2[0] + r2[1] + r2[2] + r2[3]);
  }
}

// ------- normalize + write xnb bf16 [b,c,p] (residual) and xnT bf16 [b,p,c] -------
__global__ __launch_bounds__(256) void norm_trans(const float* __restrict__ x,
                                                  const float* __restrict__ stats,
                                                  const float* __restrict__ gamma,
                                                  const float* __restrict__ beta,
                                                  u16* __restrict__ xnb,
                                                  u16* __restrict__ xnT) {
  __shared__ float tile[32][33];
  int b = blockIdx.z, c0 = blockIdx.y * 32, p0 = blockIdx.x * 32;
  int g = (b << 3) + (c0 >> 6);
  float cnt = 1.f / 262144.f;
  float mu = stats[g * 2 + 0] * cnt;
  float ms = stats[g * 2 + 1] * cnt;
  float rstd = rsqrtf(ms - mu * mu + 1e-5f);
  int tp = threadIdx.x & 31, tc = threadIdx.x >> 5;
#pragma unroll
  for (int r = 0; r < 4; r++) {
    int cl = tc + r * 8;
    int c = c0 + cl;
    long idx = ((long)(b * CDIM + c)) * NPOS + p0 + tp;
    float v = (x[idx] - mu) * rstd * gamma[c] + beta[c];
    xnb[idx] = f2bf(v);
    tile[cl][tp] = v;
  }
  __syncthreads();
#pragma unroll
  for (int r = 0; r < 4; r++) {
    int pl = tc + r * 8, cl = tp;
    xnT[((long)(b * NPOS + p0 + pl)) * CDIM + c0 + cl] = f2bf(tile[cl][pl]);
  }
}

// ------- fp32 -> bf16 weight convert (wq, wk, wv, wp all [512][512]) -------
__global__ __launch_bounds__(256) void cvt4(const float* __restrict__ a, const float* __restrict__ b,
                                            const float* __restrict__ c, const float* __restrict__ d,
                                            u16* __restrict__ oa, u16* __restrict__ ob,
                                            u16* __restrict__ oc, u16* __restrict__ od) {
  int i = blockIdx.x * 256 + threadIdx.x;
  const float* src; u16* dst;
  switch (blockIdx.y) {
    case 0: src = a; dst = oa; break;
    case 1: src = b; dst = ob; break;
    case 2: src = c; dst = oc; break;
    default: src = d; dst = od; break;
  }
  dst[i] = f2bf(src[i]);
}

// ---------------- gemm_bt: C[m,n] = sum_k A[m,k]*B[n,k]  (both K-contig, bf16) ----------------
// 128(M) x BN tile, BK=64, BN/64*2 waves (wave tile 64x64), XOR-swizzled LDS, dbuf.
// MFMA operands SWAPPED: mfma(bfr, af, acc) -> C/D lane dim = m, reg dim = n.
// MODE 0: fp8 out, + bias[n] (bias|bias1 split at n=512)    (fused QK -> fp8)
// MODE 5: fp8 out, + bias[m]                                (V fp8)
// MODE 6: f32  out = acc + bias[m] + bf16 resid             (proj + residual)
template <int MODE, int BN>
__global__ __launch_bounds__(BN * 2, 2) void gemm_bt(
    const u16* __restrict__ A, const u16* __restrict__ B,
    void* __restrict__ Cp, const float* __restrict__ bias,
    const float* __restrict__ bias1, const u16* __restrict__ residb,
    int N, int K, int lda, int ldb,
    long sA, long sB, long sC, long sR) {
  __shared__ u16 Asm[2][128 * 64];
  __shared__ u16 Bsm[2][BN * 64];
  constexpr int NT = BN * 2;       // threads
  constexpr int STEP = NT / 8;     // staging rows per round
  int bz = blockIdx.z;
  A += (long)bz * sA;
  B += (long)bz * sB;
  int bm = blockIdx.y, bn = blockIdx.x;
  int tid = threadIdx.x;
  int lane = tid & 63, wave = tid >> 6;
  int wm = (wave & 1) * 64, wn = (wave >> 1) * 64;

  int row0 = tid >> 3;             // 0..STEP-1
  int ko = (tid & 7) * 8;
  int kos = ko ^ ((row0 & 7) * 8); // STEP multiple of 8 -> row&7 invariant
  f32x4 acc[4][4] = {};
  int row16 = lane & 15;
  int kq = (lane >> 4) * 8;

  auto stage = [&](int buf, int k0) {
#pragma unroll
    for (int r = 0; r < 128 / STEP; r++) {
      int row = row0 + r * STEP;
      async16(A + (long)(bm * 128 + row) * lda + k0 + kos, &Asm[buf][row * 64 + ko]);
    }
#pragma unroll
    for (int r = 0; r < BN / STEP; r++) {
      int row = row0 + r * STEP;
      async16(B + (long)(bn * BN + row) * ldb + k0 + kos, &Bsm[buf][row * 64 + ko]);
    }
  };

  stage(0, 0);
  drain_barrier();
  int cur = 0;
  for (int k0 = 0; k0 < K; k0 += 64) {
    if (k0 + 64 < K) stage(cur ^ 1, k0 + 64);   // prefetch next tile
#pragma unroll
    for (int s2 = 0; s2 < 2; s2++) {
      bf16x8 af[4], bfr[4];
#pragma unroll
      for (int i = 0; i < 4; i++) {
        int row = wm + i * 16 + row16;
        af[i] = *(const bf16x8*)&Asm[cur][row * 64 + ((s2 * 32 + kq) ^ ((row & 7) * 8))];
      }
#pragma unroll
      for (int j = 0; j < 4; j++) {
        int row = wn + j * 16 + row16;
        bfr[j] = *(const bf16x8*)&Bsm[cur][row * 64 + ((s2 * 32 + kq) ^ ((row & 7) * 8))];
      }
      __builtin_amdgcn_s_setprio(1);
#pragma unroll
      for (int i = 0; i < 4; i++)
#pragma unroll
        for (int j = 0; j < 4; j++)
          acc[i][j] = __builtin_amdgcn_mfma_f32_16x16x32_bf16(bfr[j], af[i], acc[i][j], 0, 0, 0);
      __builtin_amdgcn_s_setprio(0);
    }
    drain_barrier();
    cur ^= 1;
  }

  // epilogue (swapped layout): m = lane&15 within tile, n = (lane>>4)*4 + reg
  int mcol = lane & 15, rb = (lane >> 4) * 4;
  long zC = (long)bz * sC;
#pragma unroll
  for (int i = 0; i < 4; i++) {
    int gm = bm * 128 + wm + i * 16 + mcol;
    float bm_add = 0.f;
    if constexpr (MODE == 5 || MODE == 6) bm_add = bias[gm];
#pragma unroll
    for (int j = 0; j < 4; j++) {
      int gn0 = bn * BN + wn + j * 16 + rb;
      long off = zC + (long)gm * N + gn0;
      float v[4];
#pragma unroll
      for (int r = 0; r < 4; r++) v[r] = acc[i][j][r];
      if constexpr (MODE == 0) {
        const float* bb = (gn0 < 512) ? (bias + gn0) : (bias1 + (gn0 - 512));
#pragma unroll
        for (int r = 0; r < 4; r++) v[r] += bb[r];
        *(unsigned*)&((u8*)Cp)[off] = pk4_fp8(v[0], v[1], v[2], v[3]);
      }
      if constexpr (MODE == 5) {
#pragma unroll
        for (int r = 0; r < 4; r++) v[r] += bm_add;
        *(unsigned*)&((u8*)Cp)[off] = pk4_fp8(v[0], v[1], v[2], v[3]);
      }
      if constexpr (MODE == 6) {
        u16x4 rv = *(const u16x4*)&residb[(long)bz * sR + (long)gm * N + gn0];
        f32x4 o;
#pragma unroll
        for (int r = 0; r < 4; r++) o[r] = v[r] + bm_add + bf2f(rv[r]);
        *(f32x4*)&((float*)Cp)[off] = o;
      }
    }
  }
}

// ---------------- fattn: fused S=exp(QK^T*scale) and H=(S.V)/rowsum ----------------
// Grid (64 i-tiles, 1, 4 batches) x 512 thr (8 waves). i-tile 64, j-tile 128,
// 32 j-steps. MX-fp8 MFMA 32x32x64 (unit scales), swapped operands (verified R2
// layout: D lane=m(l31), reg n=(r&3)+8*(r>>2)+4*h; A/B frag: lane=row l31,
// k-bytes h*32..+31).
// Per step: [sync: K_t drained] stage V_t; S-subtile(wi,wj)=Q.K^T (8 MFMA);
// exp -> P fp8 LDS [64][128] swizzled + rowsum regs; [sync: V_t drained, P
// visible] stage K_{t+1}; acc[2][2] += P.V^T (wave owns c-slice w*64, 8 MFMA).
// K,V single-buffered 64KB each (stage issued one phase ahead; reads complete
// before the barrier preceding each overwrite). Epilogue: lsum cross-wave
// reduce, H = acc/l -> bf16 [b,i,512].
__global__ __launch_bounds__(512, 2) void fattn(const u8* __restrict__ QKf8,
                                                const u8* __restrict__ Vf8,
                                                u16* __restrict__ H, float scale) {
  __shared__ u8 Ksm[65536];      // [128 j][512 B], 16B chunks, low3 ^ (j&7)
  __shared__ u8 Vsm[65536];      // [512 c][128 B], 8 chunks, ^ (c&7)
  __shared__ u8 Pp[8192];        // [64 i][128 B], 8 chunks, ^ (i&7)
  __shared__ float lsum[4][64];
  int tid = threadIdx.x, lane = tid & 63, w = tid >> 6;
  int l31 = lane & 31, h = lane >> 5;
  int wi = w >> 2, wj = w & 3;
  int bm = blockIdx.x, bz = blockIdx.z;
  const u8* QKb = QKf8 + (long)bz * 4194304;
  const u8* Vb  = Vf8 + (long)bz * 2097152;

  // Q rows (bm*64 + wi*32 + l31), full c=512, resident in regs (64 VGPR)
  i32x8 qf[8];
  {
    const u8* qrow = QKb + (long)(bm * 64 + wi * 32 + l31) * 1024 + h * 32;
#pragma unroll
    for (int s = 0; s < 8; s++) {
      i32x4 lo = *(const i32x4*)(qrow + s * 64);
      i32x4 hi = *(const i32x4*)(qrow + s * 64 + 16);
      qf[s] = __builtin_shufflevector(lo, hi, 0, 1, 2, 3, 4, 5, 6, 7);
    }
  }

  auto stageK = [&](int t) {
#pragma unroll
    for (int r = 0; r < 8; r++) {
      int zz = tid + r * 512;
      int j = zz >> 5, pos = zz & 31;
      int gch = (pos & 24) | ((pos & 7) ^ (j & 7));
      async16b(QKb + (long)(t * 128 + j) * 1024 + 512 + gch * 16, &Ksm[zz * 16]);
    }
  };
  auto stageV = [&](int t) {
#pragma unroll
    for (int r = 0; r < 8; r++) {
      int zz = tid + r * 512;
      int c = zz >> 3, pos = zz & 7;
      int gch = pos ^ (c & 7);
      async16b(Vb + (long)c * 4096 + t * 128 + gch * 16, &Vsm[zz * 16]);
    }
  };

  f32x16 acc[2][2] = {};   // [i-sub][c-sub]; wave c-base = w*64
  float rsum = 0.f;
  int i = wi * 32 + l31;   // this wave's S row (lane)
  int jr = wj * 32 + l31;  // this wave's K row (lane)

  stageK(0);

  for (int t = 0; t < 32; t++) {
    __syncthreads();              // drains K_t (+Q at t=0); Vsm/Pp reads done
    stageV(t);
    // ---- phase 1: S = Q.K^T over c=512 ----
    f32x16 s16 = {};
#pragma unroll
    for (int s = 0; s < 8; s++) {
      int p0 = 4 * s + 2 * h;
      int pos0 = (p0 & 24) | ((p0 & 7) ^ (jr & 7));
      int pos1 = (p0 & 24) | (((p0 + 1) & 7) ^ (jr & 7));
      i32x4 lo = *(const i32x4*)&Ksm[jr * 512 + pos0 * 16];
      i32x4 hi = *(const i32x4*)&Ksm[jr * 512 + pos1 * 16];
      i32x8 bfk = __builtin_shufflevector(lo, hi, 0, 1, 2, 3, 4, 5, 6, 7);
      __builtin_amdgcn_s_setprio(1);
      s16 = __builtin_amdgcn_mfma_scale_f32_32x32x64_f8f6f4(
          bfk, qf[s], s16, 0, 0, 0, 0x7F7F7F7F, 0, 0x7F7F7F7F);
      __builtin_amdgcn_s_setprio(0);
    }
    // exp + rowsum + pack P -> LDS
    float pv[16];
    float rs = 0.f;
#pragma unroll
    for (int r = 0; r < 16; r++) { pv[r] = __expf(s16[r] * scale); rs += pv[r]; }
    rsum += rs + __shfl_xor(rs, 32, 64);
#pragma unroll
    for (int g = 0; g < 4; g++) {
      int ch = wj * 2 + (g >> 1);          // local-j chunk (j = wj*32+8g+4h)
      int pos = ch ^ (i & 7);
      *(unsigned*)&Pp[i * 128 + pos * 16 + 8 * (g & 1) + 4 * h] =
          pk4_fp8(pv[4 * g], pv[4 * g + 1], pv[4 * g + 2], pv[4 * g + 3]);
    }
    __syncthreads();              // drains V_t + P ds_writes visible
    if (t < 31) stageK(t + 1);
    // ---- phase 2: acc += P.V^T over local j=128 (2 MFMA k-steps) ----
#pragma unroll
    for (int kk = 0; kk < 2; kk++) {
      i32x8 afp[2], bfv[2];
#pragma unroll
      for (int mr = 0; mr < 2; mr++) {
        int ii = mr * 32 + l31;
        int c0 = kk * 4 + h * 2;
        i32x4 lo = *(const i32x4*)&Pp[ii * 128 + ((c0) ^ (ii & 7)) * 16];
        i32x4 hi = *(const i32x4*)&Pp[ii * 128 + ((c0 + 1) ^ (ii & 7)) * 16];
        afp[mr] = __builtin_shufflevector(lo, hi, 0, 1, 2, 3, 4, 5, 6, 7);
      }
#pragma unroll
      for (int nr = 0; nr < 2; nr++) {
        int c = w * 64 + nr * 32 + l31;
        int g0 = kk * 4 + h * 2;
        i32x4 lo = *(const i32x4*)&Vsm[c * 128 + ((g0) ^ (c & 7)) * 16];
        i32x4 hi = *(const i32x4*)&Vsm[c * 128 + ((g0 + 1) ^ (c & 7)) * 16];
        bfv[nr] = __builtin_shufflevector(lo, hi, 0, 1, 2, 3, 4, 5, 6, 7);
      }
      __builtin_amdgcn_s_setprio(1);
#pragma unroll
      for (int mr = 0; mr < 2; mr++)
#pragma unroll
        for (int nr = 0; nr < 2; nr++)
          acc[mr][nr] = __builtin_amdgcn_mfma_scale_f32_32x32x64_f8f6f4(
              bfv[nr], afp[mr], acc[mr][nr], 0, 0, 0, 0x7F7F7F7F, 0, 0x7F7F7F7F);
      __builtin_amdgcn_s_setprio(0);
    }
  }

  // ---- epilogue: reduce rowsums across wj, divide, store H bf16 ----
  if (lane < 32) lsum[wj][wi * 32 + l31] = rsum;
  __syncthreads();
#pragma unroll
  for (int mr = 0; mr < 2; mr++) {
    int li = mr * 32 + l31;
    float lt = lsum[0][li] + lsum[1][li] + lsum[2][li] + lsum[3][li];
    float inv = 1.f / lt;
    long hrow = ((long)bz * NPOS + bm * 64 + li) * 512;
#pragma unroll
    for (int nr = 0; nr < 2; nr++) {
#pragma unroll
      for (int g = 0; g < 4; g++) {
        u16x4 o;
#pragma unroll
        for (int r = 0; r < 4; r++) o[r] = f2bf(acc[mr][nr][4 * g + r] * inv);
        *(u16x4*)&H[hrow + w * 64 + nr * 32 + 8 * g + 4 * h] = o;
      }
    }
  }
}

extern "C" void kernel_launch(void* const* d_in, const int* in_sizes, int n_in,
                              void* d_out, int out_size, void* d_ws, size_t ws_size,
                              hipStream_t stream) {
  const float* x     = (const float*)d_in[0];
  const float* gamma = (const float*)d_in[1];
  const float* beta  = (const float*)d_in[2];
  const float* wq = (const float*)d_in[3];
  const float* bq = (const float*)d_in[4];
  const float* wk = (const float*)d_in[5];
  const float* bk = (const float*)d_in[6];
  const float* wv = (const float*)d_in[7];
  const float* bv = (const float*)d_in[8];
  const float* wp = (const float*)d_in[9];
  const float* bp = (const float*)d_in[10];
  float* out = (float*)d_out;

  // workspace layout (bytes)
  char* W = (char*)d_ws;
  float* stats = (float*)(W + 0);               // 256 B
  u16* xnb  = (u16*)(W + 65792);                // 16,777,216 bf16 [b,c,p] residual
  u16* xnT  = (u16*)(W + 16843008);             // 16,777,216 bf16 [b,p,c]
  u16* wqkb = (u16*)(W + 33620224);             // 1,048,576  bf16 [1024(cq;ck)][512]
  u16* wvb  = (u16*)(W + 34668800);             // 524,288    bf16 [512][512]
  u16* wpb  = (u16*)(W + 35193088);             // 524,288    bf16 [512][512]
  u8*  QKf8 = (u8*)(W + 37290240);              // 16,777,216 fp8 [b,p,1024] (Q|K)
  u8*  Vf8  = (u8*)(W + 54067456);              // 8,388,608  fp8 [b,c,p]
  u16* Hws  = (u16*)(W + 62456064);             // 16,777,216 bf16 [b,i,512]
  (void)in_sizes; (void)n_in; (void)out_size; (void)ws_size;

  hipMemsetAsync(W, 0, 256, stream);   // stats
  gn_partial<<<256, 256, 0, stream>>>(x, stats);
  norm_trans<<<dim3(128, 16, 4), 256, 0, stream>>>(x, stats, gamma, beta, xnb, xnT);
  cvt4<<<dim3(1024, 4), 256, 0, stream>>>(wq, wk, wv, wp, wqkb, wqkb + 262144, wvb, wpb);

  const long NC = (long)NPOS * CDIM;    // 2,097,152
  const long CN = (long)CDIM * NPOS;
  const float scale = 0.044194173824159216f;  // 1/sqrt(512)

  // QKf8[b*p, 0:512]=Q, [512:1024]=K (fp8): A=xnT (M=16384), B=wqkb (N=1024), K=512
  gemm_bt<0, 128><<<dim3(8, 128, 1), 256, 0, stream>>>(xnT, wqkb, QKf8, bq, bk, nullptr,
      1024, CDIM, CDIM, CDIM, 0, 0, 0, 0);
  // V fp8 [b][c, p] = wv . xnT_b^T + bv  (M=512, N=4096, K=512)
  gemm_bt<5, 128><<<dim3(32, 4, 4), 256, 0, stream>>>(wvb, xnT, Vf8, bv, nullptr, nullptr,
      NPOS, CDIM, CDIM, CDIM, 0, NC, CN, 0);
  // fused attention: H[b,i,512] = softmax(Q.K^T/sqrt(c)) . V
  fattn<<<dim3(64, 1, NBATCH), 512, 0, stream>>>(QKf8, Vf8, Hws, scale);
  // out[b][c, p] = wp . H_b^T + bp + xnb  (M=512, N=4096, K=512)
  gemm_bt<6, 128><<<dim3(32, 4, 4), 256, 0, stream>>>(wpb, Hws, (void*)out, bp, nullptr, xnb,
      NPOS, CDIM, CDIM, CDIM, 0, (long)NPOS * CDIM, CN, CN);
}